// Round 4
// baseline (433.189 us; speedup 1.0000x reference)
//
#include <hip/hip_runtime.h>
#include <math.h>

// Problem constants
#define BROWS 16384
#define N0    2048
#define NCLS  12
#define NCLU  24
#define NDIM  4
#define NCOL  348          // 12 + 288 + 48
#define NPAD  384          // padded fused-column count

// Output offsets (floats): y0 [B,12] | y1_sel [B,24] | y2_sel [B,4] | Plc [B,24,12]
#define OUT0_OFF 0
#define OUT1_OFF (BROWS * NCLS)
#define OUT2_OFF (OUT1_OFF + BROWS * NCLU)
#define OUT3_OFF (OUT2_OFF + BROWS * NDIM)

typedef __attribute__((ext_vector_type(8))) short bf16x8;
typedef __attribute__((ext_vector_type(4))) float f32x4;
typedef unsigned short ushort_t;

// ---------------------------------------------------------------------------
// bf16 helpers — RNE split (identical numerics to the passing Round-2 kernel)
// ---------------------------------------------------------------------------
__device__ __forceinline__ unsigned short f2bf(float f) {   // RNE
    unsigned u = __float_as_uint(f);
    u += 0x7fffu + ((u >> 16) & 1u);
    return (unsigned short)(u >> 16);
}
__device__ __forceinline__ float bf2f(unsigned short h) {
    return __uint_as_float(((unsigned)h) << 16);
}
__device__ __forceinline__ void cvt8(float4 a, float4 b, bf16x8& h, bf16x8& l) {
    float f[8] = {a.x, a.y, a.z, a.w, b.x, b.y, b.z, b.w};
    #pragma unroll
    for (int i = 0; i < 8; ++i) {
        unsigned short hi = f2bf(f[i]);
        h[i] = (short)hi;
        l[i] = (short)f2bf(f[i] - bf2f(hi));
    }
}

// ---------------------------------------------------------------------------
// Kernel 1: repack fused weight matrix -> N-major bf16 hi/lo + fp32 bias
// ---------------------------------------------------------------------------
__global__ void jcp_repack2(const float* __restrict__ W_fc, const float* __restrict__ b_fc,
                            const float* __restrict__ W_bin, const float* __restrict__ b_bin,
                            const float* __restrict__ W_res, const float* __restrict__ b_res,
                            ushort_t* __restrict__ Wh, ushort_t* __restrict__ Wl,
                            float* __restrict__ bias) {
    int idx = blockIdx.x * 256 + threadIdx.x;
    if (idx >= NPAD * N0) return;
    int j = idx >> 11;
    int d = idx & 2047;
    float w = 0.0f;
    if (j < NCLS) {
        w = W_fc[d * NCLS + j];
    } else if (j < 12 + NCLU * NCLS) {
        int jj = j - 12;
        int k = jj / NCLS, c = jj - k * NCLS;
        w = W_bin[((size_t)c * N0 + d) * NCLU + k];
    } else if (j < NCOL) {
        int jj = j - 300;
        int n = jj / NCLS, c = jj - n * NCLS;
        w = W_res[((size_t)c * N0 + d) * NDIM + n];
    }
    unsigned short h = f2bf(w);
    Wh[idx] = h;
    Wl[idx] = f2bf(w - bf2f(h));

    if (idx < NPAD) {
        int jb = idx;
        float bv = 0.0f;
        if (jb < NCLS) {
            bv = b_fc[jb];
        } else if (jb < 12 + NCLU * NCLS) {
            int jj = jb - 12;
            int k = jj / NCLS, c = jj - k * NCLS;
            bv = b_bin[c * NCLU + k];
        } else if (jb < NCOL) {
            int jj = jb - 300;
            int n = jj / NCLS, c = jj - n * NCLS;
            bv = b_res[c * NDIM + n];
        }
        bias[jb] = bv;
    }
}

// ---------------------------------------------------------------------------
// Kernel 2: split-bf16 MFMA GEMM v3 (RNE split).
//   Block: 256 thr (4 waves), tile 64 rows x 96 cols. Grid (4, 256).
//   A: fp32 -> bf16 hi/lo converted ONCE per block into LDS (dbuf, 80B rows).
//   B: bf16 hi/lo, register double-buffer from L2. x prefetch depth 2.
//   Wave tile: 32 rows (2 MFMA row-tiles) x 48 cols (3 col-tiles).
// ---------------------------------------------------------------------------
__global__ __launch_bounds__(256, 4) void jcp_gemm3(const float* __restrict__ x,
                                                    const ushort_t* __restrict__ Wh,
                                                    const ushort_t* __restrict__ Wl,
                                                    const float* __restrict__ bias,
                                                    float* __restrict__ Y) {
    __shared__ short AhB[2][64 * 40];   // 40 shorts = 80 B padded row (32 k bf16 + pad)
    __shared__ short AlB[2][64 * 40];

    const int tid  = threadIdx.x;
    const int wid  = tid >> 6;
    const int lane = tid & 63;
    const int quad = lane >> 4;
    const int l16  = lane & 15;
    const int wrow = (wid & 1) * 32;
    const int wcol = (wid >> 1) * 48;
    const int rbase = blockIdx.y * 64;
    const int jbase = blockIdx.x * 96;

    // staging assignment: thread -> (row 0..63, k-octet 0..3)
    const int srow = tid >> 2;
    const int sk   = (tid & 3) * 8;
    const float* xg = x + (size_t)(rbase + srow) * N0 + sk;
    const int soff = srow * 40 + sk;

    const size_t cb = (size_t)(jbase + wcol + l16) * N0 + quad * 8;
    const ushort_t* pWh = Wh + cb;
    const ushort_t* pWl = Wl + cb;
    const int TJ = 16 * N0;

    f32x4 acc[2][3];
    #pragma unroll
    for (int i = 0; i < 2; ++i)
        #pragma unroll
        for (int j = 0; j < 3; ++j)
            acc[i][j] = f32x4{0.f, 0.f, 0.f, 0.f};

    bf16x8 Bh[2][3], Bl[2][3];
    #pragma unroll
    for (int j = 0; j < 3; ++j) {
        Bh[0][j] = *(const bf16x8*)(pWh + j * TJ);
        Bl[0][j] = *(const bf16x8*)(pWl + j * TJ);
    }
    // iter-0 A: load, convert, stage
    {
        float4 a = *(const float4*)(xg);
        float4 b = *(const float4*)(xg + 4);
        bf16x8 h, l;
        cvt8(a, b, h, l);
        *(bf16x8*)&AhB[0][soff] = h;
        *(bf16x8*)&AlB[0][soff] = l;
    }
    // iter-1 x in regs
    float4 xn0 = *(const float4*)(xg + 32);
    float4 xn1 = *(const float4*)(xg + 36);
    __syncthreads();

    auto body = [&](int it, int p) {
        // prefetch x for it+2
        float4 xf0 = xn0, xf1 = xn1;
        if (it < 62) {
            xf0 = *(const float4*)(xg + (it + 2) * 32);
            xf1 = *(const float4*)(xg + (it + 2) * 32 + 4);
        }
        // prefetch B for it+1 (L2-resident)
        if (it < 63) {
            #pragma unroll
            for (int j = 0; j < 3; ++j) {
                Bh[p ^ 1][j] = *(const bf16x8*)(pWh + (it + 1) * 32 + j * TJ);
                Bl[p ^ 1][j] = *(const bf16x8*)(pWl + (it + 1) * 32 + j * TJ);
            }
        }
        // A fragments from LDS
        bf16x8 fAh[2], fAl[2];
        #pragma unroll
        for (int i = 0; i < 2; ++i) {
            const int ro = (wrow + i * 16 + l16) * 40 + quad * 8;
            fAh[i] = *(const bf16x8*)&AhB[p][ro];
            fAl[i] = *(const bf16x8*)&AlB[p][ro];
        }
        // 18 MFMAs (3 split terms x 2 row-tiles x 3 col-tiles)
        #pragma unroll
        for (int j = 0; j < 3; ++j)
            #pragma unroll
            for (int i = 0; i < 2; ++i) {
                acc[i][j] = __builtin_amdgcn_mfma_f32_16x16x32_bf16(fAh[i], Bh[p][j], acc[i][j], 0, 0, 0);
                acc[i][j] = __builtin_amdgcn_mfma_f32_16x16x32_bf16(fAl[i], Bh[p][j], acc[i][j], 0, 0, 0);
                acc[i][j] = __builtin_amdgcn_mfma_f32_16x16x32_bf16(fAh[i], Bl[p][j], acc[i][j], 0, 0, 0);
            }
        // convert + stage A for it+1 into the other buffer
        if (it < 63) {
            bf16x8 h, l;
            cvt8(xn0, xn1, h, l);
            *(bf16x8*)&AhB[p ^ 1][soff] = h;
            *(bf16x8*)&AlB[p ^ 1][soff] = l;
        }
        __syncthreads();
        xn0 = xf0; xn1 = xf1;
    };

    for (int it = 0; it < 64; it += 2) { body(it, 0); body(it + 1, 1); }

    // Epilogue: C/D layout col = lane&15, row = quad*4 + reg
    #pragma unroll
    for (int j = 0; j < 3; ++j) {
        const int col = jbase + wcol + 16 * j + l16;
        const float bj = bias[col];
        #pragma unroll
        for (int i = 0; i < 2; ++i) {
            float* yp = Y + (size_t)(rbase + wrow + i * 16 + quad * 4) * NPAD + col;
            yp[0 * NPAD] = acc[i][j][0] + bj;
            yp[1 * NPAD] = acc[i][j][1] + bj;
            yp[2 * NPAD] = acc[i][j][2] + bj;
            yp[3 * NPAD] = acc[i][j][3] + bj;
        }
    }
}

// ---------------------------------------------------------------------------
// Kernel 3: head v3. Block = 256 thr = 16 rows x 16 lanes (lane = class).
//   Stage 16 Y-rows into LDS (coalesced float4), compute from LDS, write Plc
//   back into the (reused) LDS rows, store out3 with coalesced float4.
// ---------------------------------------------------------------------------
#define LROW 388   // padded LDS row stride (floats)

__global__ __launch_bounds__(256) void jcp_head3(const float* __restrict__ Y,
                                                 float* __restrict__ out) {
    __shared__ float Ly[16 * LROW];
    const int tid = threadIdx.x;
    const int r0  = blockIdx.x * 16;

    // stage 16 rows x 384 floats, coalesced
    #pragma unroll
    for (int jj = 0; jj < 6; ++jj) {
        int f = tid + jj * 256;          // float4 id 0..1535
        int row = f / 96, c4 = f - row * 96;
        float4 v = *(const float4*)(Y + (size_t)(r0 + row) * NPAD + c4 * 4);
        *(float4*)&Ly[row * LROW + c4 * 4] = v;
    }
    __syncthreads();

    const int grp = tid >> 4;
    const int c   = tid & 15;
    const bool on = (c < NCLS);
    const int r   = r0 + grp;
    const float* y = &Ly[grp * LROW];

    // category softmax (cross-lane width 16)
    float y0c = on ? y[c] : -INFINITY;
    float m0 = y0c;
    #pragma unroll
    for (int m = 8; m >= 1; m >>= 1) m0 = fmaxf(m0, __shfl_xor(m0, m, 16));
    float e0 = on ? expf(y0c - m0) : 0.0f;
    float s0 = e0;
    #pragma unroll
    for (int m = 8; m >= 1; m >>= 1) s0 += __shfl_xor(s0, m, 16);
    const float Pc = e0 / s0;

    // per-class cluster values
    float v[NCLU];
    float mc = -INFINITY;
    #pragma unroll
    for (int k = 0; k < NCLU; ++k) {
        v[k] = y[12 + k * NCLS + c];
        mc = fmaxf(mc, v[k]);
    }
    float sc = 0.0f;
    #pragma unroll
    for (int k = 0; k < NCLU; ++k) sc += expf(v[k] - mc);
    const float rs = Pc / sc;

    // y2 candidates before the row gets overwritten by Plc
    float y2c[NDIM];
    #pragma unroll
    for (int n = 0; n < NDIM; ++n) y2c[n] = y[300 + n * NCLS + c];

    // Plc into LDS (reuse cols 0..287 of own row) + per-class best
    float best = -INFINITY;
    int bk = 0;
    float* lrow = &Ly[grp * LROW];
    #pragma unroll
    for (int k = 0; k < NCLU; ++k) {
        const float p = expf(v[k] - mc) * rs;
        if (on) lrow[k * NCLS + c] = p;
        if (p > best) { best = p; bk = k; }
    }
    int flat = bk * NCLS + c;
    if (!on) { best = -INFINITY; flat = 1 << 30; }

    // cross-lane joint argmax: larger p wins; tie -> smaller flat index
    #pragma unroll
    for (int m = 8; m >= 1; m >>= 1) {
        const float op = __shfl_xor(best, m, 16);
        const int   of = __shfl_xor(flat, m, 16);
        if (op > best || (op == best && of < flat)) { best = op; flat = of; }
    }
    const int ic = flat % NCLS;

    if (on) out[OUT0_OFF + (size_t)r * NCLS + c] = y0c;
    if (c == ic) {
        float* o1 = out + OUT1_OFF + (size_t)r * NCLU;
        #pragma unroll
        for (int k = 0; k < NCLU; ++k) o1[k] = v[k];
        float* o2 = out + OUT2_OFF + (size_t)r * NDIM;
        #pragma unroll
        for (int n = 0; n < NDIM; ++n) o2[n] = y2c[n];
    }

    __syncthreads();
    // coalesced out3 store: 16 rows x 288 floats = 1152 float4
    #pragma unroll
    for (int jj = 0; jj < 5; ++jj) {
        int f = tid + jj * 256;
        if (f < 1152) {
            int row = f / 72, c4 = f - row * 72;
            *(float4*)(out + OUT3_OFF + (size_t)(r0 + row) * (NCLU * NCLS) + c4 * 4) =
                *(float4*)&Ly[row * LROW + c4 * 4];
        }
    }
}

// ---------------------------------------------------------------------------
extern "C" void kernel_launch(void* const* d_in, const int* in_sizes, int n_in,
                              void* d_out, int out_size, void* d_ws, size_t ws_size,
                              hipStream_t stream) {
    const float* x     = (const float*)d_in[0];
    const float* W_fc  = (const float*)d_in[1];
    const float* b_fc  = (const float*)d_in[2];
    const float* W_bin = (const float*)d_in[3];
    const float* b_bin = (const float*)d_in[4];
    const float* W_res = (const float*)d_in[5];
    const float* b_res = (const float*)d_in[6];
    float* out = (float*)d_out;

    // ws layout
    ushort_t* Wh   = (ushort_t*)d_ws;                  // 384*2048 bf16
    ushort_t* Wl   = Wh + NPAD * N0;                   // 384*2048 bf16
    float*    bias = (float*)(Wl + NPAD * N0);         // 384 fp32
    float*    Yb   = bias + NPAD;                      // 16384*384 fp32

    jcp_repack2<<<(NPAD * N0 + 255) / 256, 256, 0, stream>>>(W_fc, b_fc, W_bin, b_bin,
                                                             W_res, b_res, Wh, Wl, bias);
    dim3 grid(NPAD / 96, BROWS / 64);   // (4, 256)
    jcp_gemm3<<<grid, 256, 0, stream>>>(x, Wh, Wl, bias, Yb);
    jcp_head3<<<BROWS / 16, 256, 0, stream>>>(Yb, out);
}

// Round 5
// 317.946 us; speedup vs baseline: 1.3625x; 1.3625x over previous
//
#include <hip/hip_runtime.h>
#include <math.h>

// Problem constants
#define BROWS 16384
#define N0    2048
#define NCLS  12
#define NCLU  24
#define NDIM  4
#define NCOL  348          // 12 + 288 + 48
#define NPAD  384          // padded fused-column count (24 col-tiles of 16)
#define NTILE 24           // NPAD/16

// Output offsets (floats): y0 [B,12] | y1_sel [B,24] | y2_sel [B,4] | Plc [B,24,12]
#define OUT0_OFF 0
#define OUT1_OFF (BROWS * NCLS)
#define OUT2_OFF (OUT1_OFF + BROWS * NCLU)
#define OUT3_OFF (OUT2_OFF + BROWS * NDIM)

typedef __attribute__((ext_vector_type(8))) short bf16x8;
typedef __attribute__((ext_vector_type(4))) float f32x4;
typedef unsigned short ushort_t;

// ---------------------------------------------------------------------------
// bf16 helpers — RNE split (bit-identical to the passing Round-2 numerics)
// ---------------------------------------------------------------------------
__device__ __forceinline__ unsigned short f2bf(float f) {   // RNE
    unsigned u = __float_as_uint(f);
    u += 0x7fffu + ((u >> 16) & 1u);
    return (unsigned short)(u >> 16);
}
__device__ __forceinline__ float bf2f(unsigned short h) {
    return __uint_as_float(((unsigned)h) << 16);
}
__device__ __forceinline__ void cvt8(float4 a, float4 b, bf16x8& h, bf16x8& l) {
    float f[8] = {a.x, a.y, a.z, a.w, b.x, b.y, b.z, b.w};
    #pragma unroll
    for (int i = 0; i < 8; ++i) {
        unsigned short hi = f2bf(f[i]);
        h[i] = (short)hi;
        l[i] = (short)f2bf(f[i] - bf2f(hi));
    }
}

__device__ __forceinline__ void load_lds16(const void* g, void* l) {
    __builtin_amdgcn_global_load_lds((const __attribute__((address_space(1))) void*)g,
                                     (__attribute__((address_space(3))) void*)l, 16, 0, 0);
}

__device__ __forceinline__ float fused_w(const float* __restrict__ W_fc,
                                         const float* __restrict__ W_bin,
                                         const float* __restrict__ W_res,
                                         int col, int d) {
    float w = 0.0f;
    if (col < NCLS) {
        w = W_fc[d * NCLS + col];
    } else if (col < 12 + NCLU * NCLS) {
        int jj = col - 12;
        int k = jj / NCLS, c = jj - k * NCLS;
        w = W_bin[((size_t)c * N0 + d) * NCLU + k];
    } else if (col < NCOL) {
        int jj = col - 300;
        int n = jj / NCLS, c = jj - n * NCLS;
        w = W_res[((size_t)c * N0 + d) * NDIM + n];
    }
    return w;
}

// ---------------------------------------------------------------------------
// Kernel 1: repack fused weights straight into MFMA-fragment streaming order.
//   Bp{h,l}[((J*64 + kb)*64 + lane)*8 + i] = W[col = J*16 + (lane&15)]
//                                             [k  = kb*32 + (lane>>4)*8 + i]
//   One thread per (J,kb,lane) writes one bf16x8 to each of hi/lo.
// ---------------------------------------------------------------------------
__global__ void jcp_repack3(const float* __restrict__ W_fc, const float* __restrict__ b_fc,
                            const float* __restrict__ W_bin, const float* __restrict__ b_bin,
                            const float* __restrict__ W_res, const float* __restrict__ b_res,
                            ushort_t* __restrict__ Bph, ushort_t* __restrict__ Bpl,
                            float* __restrict__ bias) {
    int t = blockIdx.x * 256 + threadIdx.x;          // 0 .. 98303
    if (t >= NTILE * 64 * 64) return;
    const int lane = t & 63;
    const int kb   = (t >> 6) & 63;
    const int J    = t >> 12;
    const int col  = J * 16 + (lane & 15);
    const int k0   = kb * 32 + (lane >> 4) * 8;

    bf16x8 h, l;
    #pragma unroll
    for (int i = 0; i < 8; ++i) {
        float w = fused_w(W_fc, W_bin, W_res, col, k0 + i);
        unsigned short hi = f2bf(w);
        h[i] = (short)hi;
        l[i] = (short)f2bf(w - bf2f(hi));
    }
    *(bf16x8*)(Bph + (size_t)t * 8) = h;
    *(bf16x8*)(Bpl + (size_t)t * 8) = l;

    if (t < NPAD) {
        int jb = t;
        float bv = 0.0f;
        if (jb < NCLS) {
            bv = b_fc[jb];
        } else if (jb < 12 + NCLU * NCLS) {
            int jj = jb - 12;
            int k = jj / NCLS, c = jj - k * NCLS;
            bv = b_bin[c * NCLU + k];
        } else if (jb < NCOL) {
            int jj = jb - 300;
            int n = jj / NCLS, c = jj - n * NCLS;
            bv = b_res[c * NDIM + n];
        }
        bias[jb] = bv;
    }
}

// ---------------------------------------------------------------------------
// Kernel 2: split-bf16 MFMA GEMM v4.
//   Grid (4, 256), block 256 thr = 4 waves, tile 64 rows x 96 cols.
//   Wave tile: 32 rows x 48 cols (2 row-tiles x 3 col-tiles), acc = 24 VGPR.
//   x: raw fp32 -> LDS via global_load_lds (dbuf 2x8KB), XOR chunk swizzle
//      (c' = c ^ (row&7)) so frag ds_read_b128 is 2-way max (free).
//   B: single-buffered regs from pre-swizzled fragment layout (coalesced).
// ---------------------------------------------------------------------------
__global__ __launch_bounds__(256, 4) void jcp_gemm4(const float* __restrict__ x,
                                                    const ushort_t* __restrict__ Bph,
                                                    const ushort_t* __restrict__ Bpl,
                                                    const float* __restrict__ bias,
                                                    float* __restrict__ Y) {
    __shared__ float Lx[2 * 2048];    // 2 bufs x 64 rows x 32 floats (8 KB each)

    const int tid  = threadIdx.x;
    const int wid  = tid >> 6;
    const int lane = tid & 63;
    const int quad = lane >> 4;
    const int l16  = lane & 15;
    const int wrow = (wid & 1) * 32;          // row half
    const int wct  = (wid >> 1) * 3;          // first col-tile (of 6 in block)
    const int rbase = blockIdx.y * 64;
    const int jbase = blockIdx.x * 96;

    // --- DMA source addresses (2 insts/wave, 8 rows x 32 floats each) ---
    const int dr = lane >> 3;                 // 0..7 row within inst
    const int dc = (lane & 7) ^ dr;           // swizzled chunk (16B units)
    const float* gsrc0 = x + (size_t)(rbase + 8 * (2 * wid) + dr) * N0 + dc * 4;
    const float* gsrc1 = x + (size_t)(rbase + 8 * (2 * wid + 1) + dr) * N0 + dc * 4;
    const int ldst0 = (2 * wid) * 256;        // float offset of inst dest in buf
    const int ldst1 = (2 * wid + 1) * 256;

    // --- fragment read offsets (floats) ---
    const int s = l16 & 7;
    const int pos1 = (2 * quad) ^ s;
    const int o1 = pos1 * 4;
    const int o2 = (pos1 ^ 1) * 4;
    const int ro0 = (wrow + l16) * 32;
    const int ro1 = (wrow + 16 + l16) * 32;

    // --- B per-lane pointers, fragment-order arrays ---
    const ushort_t* pBh = Bph + (size_t)lane * 8;
    const ushort_t* pBl = Bpl + (size_t)lane * 8;
    int Jt[3];
    #pragma unroll
    for (int j = 0; j < 3; ++j) Jt[j] = (jbase / 16 + wct + j) * 32768;

    f32x4 acc[2][3];
    #pragma unroll
    for (int i = 0; i < 2; ++i)
        #pragma unroll
        for (int j = 0; j < 3; ++j)
            acc[i][j] = f32x4{0.f, 0.f, 0.f, 0.f};

    // stage it=0 into buf 0 (barrier's vmcnt(0) drain completes the DMA)
    load_lds16(gsrc0, &Lx[ldst0]);
    load_lds16(gsrc1, &Lx[ldst1]);
    __syncthreads();

    int p = 0;
    for (int it = 0; it < 64; ++it) {
        // B fragments for this iter (single-buffered, L2-resident, coalesced)
        bf16x8 bh[3], bl[3];
        #pragma unroll
        for (int j = 0; j < 3; ++j) {
            bh[j] = *(const bf16x8*)(pBh + Jt[j] + it * 512);
            bl[j] = *(const bf16x8*)(pBl + Jt[j] + it * 512);
        }
        // async-stage x for it+1 into the other buffer
        if (it < 63) {
            load_lds16(gsrc0 + (it + 1) * 32, &Lx[(p ^ 1) * 2048 + ldst0]);
            load_lds16(gsrc1 + (it + 1) * 32, &Lx[(p ^ 1) * 2048 + ldst1]);
        }
        // A fragments: raw fp32 from LDS (swizzled), convert to hi/lo
        const int pb = p * 2048;
        float4 f0a = *(const float4*)&Lx[pb + ro0 + o1];
        float4 f0b = *(const float4*)&Lx[pb + ro0 + o2];
        float4 f1a = *(const float4*)&Lx[pb + ro1 + o1];
        float4 f1b = *(const float4*)&Lx[pb + ro1 + o2];
        bf16x8 Ah[2], Al[2];
        cvt8(f0a, f0b, Ah[0], Al[0]);
        cvt8(f1a, f1b, Ah[1], Al[1]);

        // 18 MFMAs: per-accumulator order hh -> lh -> hl (R2-identical)
        #pragma unroll
        for (int j = 0; j < 3; ++j)
            #pragma unroll
            for (int i = 0; i < 2; ++i) {
                acc[i][j] = __builtin_amdgcn_mfma_f32_16x16x32_bf16(Ah[i], bh[j], acc[i][j], 0, 0, 0);
                acc[i][j] = __builtin_amdgcn_mfma_f32_16x16x32_bf16(Al[i], bh[j], acc[i][j], 0, 0, 0);
                acc[i][j] = __builtin_amdgcn_mfma_f32_16x16x32_bf16(Ah[i], bl[j], acc[i][j], 0, 0, 0);
            }
        __syncthreads();   // drains DMA (vmcnt(0)) + guards buffer reuse
        p ^= 1;
    }

    // Epilogue: C/D layout col = lane&15, row = quad*4 + reg
    #pragma unroll
    for (int j = 0; j < 3; ++j) {
        const int col = jbase + wct * 16 + 16 * j + l16;
        const float bj = bias[col];
        #pragma unroll
        for (int i = 0; i < 2; ++i) {
            float* yp = Y + (size_t)(rbase + wrow + i * 16 + quad * 4) * NPAD + col;
            yp[0 * NPAD] = acc[i][j][0] + bj;
            yp[1 * NPAD] = acc[i][j][1] + bj;
            yp[2 * NPAD] = acc[i][j][2] + bj;
            yp[3 * NPAD] = acc[i][j][3] + bj;
        }
    }
}

// ---------------------------------------------------------------------------
// Kernel 3: head. Block = 256 thr = 16 rows x 16 lanes (lane = class).
// ---------------------------------------------------------------------------
#define LROW 388   // padded LDS row stride (floats)

__global__ __launch_bounds__(256) void jcp_head3(const float* __restrict__ Y,
                                                 float* __restrict__ out) {
    __shared__ float Ly[16 * LROW];
    const int tid = threadIdx.x;
    const int r0  = blockIdx.x * 16;

    #pragma unroll
    for (int jj = 0; jj < 6; ++jj) {
        int f = tid + jj * 256;
        int row = f / 96, c4 = f - row * 96;
        float4 v = *(const float4*)(Y + (size_t)(r0 + row) * NPAD + c4 * 4);
        *(float4*)&Ly[row * LROW + c4 * 4] = v;
    }
    __syncthreads();

    const int grp = tid >> 4;
    const int c   = tid & 15;
    const bool on = (c < NCLS);
    const int r   = r0 + grp;
    const float* y = &Ly[grp * LROW];

    float y0c = on ? y[c] : -INFINITY;
    float m0 = y0c;
    #pragma unroll
    for (int m = 8; m >= 1; m >>= 1) m0 = fmaxf(m0, __shfl_xor(m0, m, 16));
    float e0 = on ? expf(y0c - m0) : 0.0f;
    float s0 = e0;
    #pragma unroll
    for (int m = 8; m >= 1; m >>= 1) s0 += __shfl_xor(s0, m, 16);
    const float Pc = e0 / s0;

    float v[NCLU];
    float mc = -INFINITY;
    #pragma unroll
    for (int k = 0; k < NCLU; ++k) {
        v[k] = y[12 + k * NCLS + c];
        mc = fmaxf(mc, v[k]);
    }
    float sc = 0.0f;
    #pragma unroll
    for (int k = 0; k < NCLU; ++k) sc += expf(v[k] - mc);
    const float rs = Pc / sc;

    float y2c[NDIM];
    #pragma unroll
    for (int n = 0; n < NDIM; ++n) y2c[n] = y[300 + n * NCLS + c];

    float best = -INFINITY;
    int bk = 0;
    float* lrow = &Ly[grp * LROW];
    #pragma unroll
    for (int k = 0; k < NCLU; ++k) {
        const float p = expf(v[k] - mc) * rs;
        if (on) lrow[k * NCLS + c] = p;
        if (p > best) { best = p; bk = k; }
    }
    int flat = bk * NCLS + c;
    if (!on) { best = -INFINITY; flat = 1 << 30; }

    #pragma unroll
    for (int m = 8; m >= 1; m >>= 1) {
        const float op = __shfl_xor(best, m, 16);
        const int   of = __shfl_xor(flat, m, 16);
        if (op > best || (op == best && of < flat)) { best = op; flat = of; }
    }
    const int ic = flat % NCLS;

    if (on) out[OUT0_OFF + (size_t)r * NCLS + c] = y0c;
    if (c == ic) {
        float* o1 = out + OUT1_OFF + (size_t)r * NCLU;
        #pragma unroll
        for (int k = 0; k < NCLU; ++k) o1[k] = v[k];
        float* o2 = out + OUT2_OFF + (size_t)r * NDIM;
        #pragma unroll
        for (int n = 0; n < NDIM; ++n) o2[n] = y2c[n];
    }

    __syncthreads();
    #pragma unroll
    for (int jj = 0; jj < 5; ++jj) {
        int f = tid + jj * 256;
        if (f < 1152) {
            int row = f / 72, c4 = f - row * 72;
            *(float4*)(out + OUT3_OFF + (size_t)(r0 + row) * (NCLU * NCLS) + c4 * 4) =
                *(float4*)&Ly[row * LROW + c4 * 4];
        }
    }
}

// ---------------------------------------------------------------------------
extern "C" void kernel_launch(void* const* d_in, const int* in_sizes, int n_in,
                              void* d_out, int out_size, void* d_ws, size_t ws_size,
                              hipStream_t stream) {
    const float* x     = (const float*)d_in[0];
    const float* W_fc  = (const float*)d_in[1];
    const float* b_fc  = (const float*)d_in[2];
    const float* W_bin = (const float*)d_in[3];
    const float* b_bin = (const float*)d_in[4];
    const float* W_res = (const float*)d_in[5];
    const float* b_res = (const float*)d_in[6];
    float* out = (float*)d_out;

    // ws layout
    ushort_t* Bph  = (ushort_t*)d_ws;                  // 24*64*64*8 bf16 = 1.5 MB
    ushort_t* Bpl  = Bph + NTILE * 64 * 64 * 8;        // 1.5 MB
    float*    bias = (float*)(Bpl + NTILE * 64 * 64 * 8);
    float*    Yb   = bias + NPAD;                      // 16384*384 fp32

    jcp_repack3<<<384, 256, 0, stream>>>(W_fc, b_fc, W_bin, b_bin, W_res, b_res,
                                         Bph, Bpl, bias);
    dim3 grid(NPAD / 96, BROWS / 64);   // (4, 256)
    jcp_gemm4<<<grid, 256, 0, stream>>>(x, Bph, Bpl, bias, Yb);
    jcp_head3<<<BROWS / 16, 256, 0, stream>>>(Yb, out);
}